// Round 11
// baseline (1123.278 us; speedup 1.0000x reference)
//
#include <hip/hip_runtime.h>

// RVQ: z [16,64,4096] f32, codebooks [8,1024,64] f32 -> zq + 8 losses + 8 perplexities
#define S      8
#define K      1024
#define D      64
#define NVEC   65536
#define NB     2048      // blocks; 32 vectors each, 2 waves split the k-range
#define NELEM  4194304.0f
#define EPSQ   1e-10f
#define DELTA  0.005f    // exact-rescan margin >> split-bf16 score error (~2e-3 worst)

typedef __attribute__((ext_vector_type(8))) short  short8;   // 8 bf16
typedef __attribute__((ext_vector_type(4))) float  float4v;  // MFMA acc

static __device__ inline unsigned short f2bf(float f) {
    unsigned int u = __float_as_uint(f);
    u = (u + 0x7FFFu + ((u >> 16) & 1u)) >> 16;
    return (unsigned short)u;
}
static __device__ inline float bf2f(unsigned short h) {
    return __uint_as_float(((unsigned int)h) << 16);
}

// ---------------------------------------------------------------------------
// Prep: (a) c2 + zero cnt; (b) interleave codebook into B-fragment streaming
// records: per (stage, tile of 16 cw) a 4 KB record of 4 segments
// [h0hi][h1hi][h0lo][h1lo]; slot l holds cw=tile*16+(l&15),
// dims h*32+(l>>4)*8+0..7 as bf16x8 -> main kernel reads base+l*16 coalesced.
// ---------------------------------------------------------------------------
__global__ void rvq_prep(const float* __restrict__ cb,
                         unsigned short* __restrict__ cbi,
                         float* __restrict__ c2, unsigned* __restrict__ cnt) {
    int i = blockIdx.x * blockDim.x + threadIdx.x;   // 0..32767
    if (i < S * K) {   // c2 + cnt zero
        const float* row = cb + (size_t)i * D;
        float a0 = 0.f, a1 = 0.f, a2 = 0.f, a3 = 0.f;
#pragma unroll
        for (int d = 0; d < D; d += 4) {
            a0 = fmaf(row[d+0], row[d+0], a0);
            a1 = fmaf(row[d+1], row[d+1], a1);
            a2 = fmaf(row[d+2], row[d+2], a2);
            a3 = fmaf(row[d+3], row[d+3], a3);
        }
        c2[i] = (a0 + a1) + (a2 + a3);
        cnt[i] = 0u;
    }
    // interleave: i = s*4096 + tau*64 + l
    int s  = i >> 12;
    int tau = (i >> 6) & 63;
    int l  = i & 63;
    int m  = l & 15, qq = l >> 4;
    const float* row = cb + (size_t)(s * K + tau * 16 + m) * D;
    short8 h0h, h0l, h1h, h1l;
#pragma unroll
    for (int e = 0; e < 8; ++e) {
        float x = row[qq * 8 + e];
        unsigned short h = f2bf(x);
        h0h[e] = (short)h; h0l[e] = (short)f2bf(x - bf2f(h));
        float y = row[32 + qq * 8 + e];
        unsigned short g = f2bf(y);
        h1h[e] = (short)g; h1l[e] = (short)f2bf(y - bf2f(g));
    }
    unsigned short* rec = cbi + (size_t)(s * 64 + tau) * 2048 + l * 8;
    *(short8*)(rec +    0) = h0h;
    *(short8*)(rec +  512) = h1h;
    *(short8*)(rec + 1024) = h0l;
    *(short8*)(rec + 1536) = h1l;
}

// ---------------------------------------------------------------------------
// Main: block = 2 waves x 32 vectors (shared). Wave w scans k-tiles
// [32w, 32w+32) — same total MFMA/VALU/L2 traffic as R9 but 2x resident
// waves for latency cover. Cross-wave top-2 merge now exchanges ALL 16
// rows per set (R10 bug: only lane 0's rows 0-3 were exchanged -> rows
// 4-15 merged foreign-row garbage; the scalar pass threshold masked the
// zq/loss corruption and only perplexity exposed it). The merge is
// symmetric (min + lowest-k tie) so both waves converge to identical
// state -> identical rescues/residuals (lockstep invariant).
// ---------------------------------------------------------------------------
__global__ __launch_bounds__(128, 3)
void rvq_main(const float* __restrict__ z, const float* __restrict__ cbf,
              const unsigned short* __restrict__ cbi,
              const float* __restrict__ c2, float* __restrict__ zq,
              float* __restrict__ lossp, unsigned* __restrict__ cnt) {
    __shared__ float lds_b1[2][2][16];
    __shared__ float lds_b2[2][2][16];
    __shared__ int   lds_k [2][2][16];

    const int tid  = threadIdx.x;
    const int lane = tid & 63;
    const int wave = tid >> 6;
    const int m    = lane & 15;
    const int q    = lane >> 4;
    const int wid  = blockIdx.x;
    const int vbase = wid * 32;
    const int b    = vbase >> 12;
    const int ta   = (vbase & 4095) + m;        // set-a t
    const int tb   = ta + 16;                   // set-b t
    const size_t zrow = ((size_t)(b * 64)) << 12;
    const int tbeg = wave * 32;                 // this wave's k-tile range
    const int tend = tbeg + 32;

    float ra0[8], ra1[8], rb0[8], rb1[8];
#pragma unroll
    for (int i = 0; i < 8; ++i) {
        ra0[i] = z[zrow + ((size_t)(q*8+i)    << 12) + ta];
        ra1[i] = z[zrow + ((size_t)(32+q*8+i) << 12) + ta];
        rb0[i] = z[zrow + ((size_t)(q*8+i)    << 12) + tb];
        rb1[i] = z[zrow + ((size_t)(32+q*8+i) << 12) + tb];
    }

#define LOADTILE(B0v, B1v, B2v, B3v, CCv, tt) {                              \
        const unsigned short* p_ = recs + (size_t)(tt) * 2048 + lane * 8;    \
        B0v = *(const short8*)(p_);                                          \
        B1v = *(const short8*)(p_ + 512);                                    \
        B2v = *(const short8*)(p_ + 1024);                                   \
        B3v = *(const short8*)(p_ + 1536);                                   \
        CCv = c2s[(tt) * 16 + m]; }

#pragma unroll 1
    for (int s = 0; s < S; ++s) {
        // split residuals to bf16 hi/lo A-fragments
        short8 xa0h, xa0l, xa1h, xa1l, xb0h, xb0l, xb1h, xb1l;
#pragma unroll
        for (int i = 0; i < 8; ++i) {
            unsigned short h;
            h = f2bf(ra0[i]); xa0h[i] = (short)h; xa0l[i] = (short)f2bf(ra0[i] - bf2f(h));
            h = f2bf(ra1[i]); xa1h[i] = (short)h; xa1l[i] = (short)f2bf(ra1[i] - bf2f(h));
            h = f2bf(rb0[i]); xb0h[i] = (short)h; xb0l[i] = (short)f2bf(rb0[i] - bf2f(h));
            h = f2bf(rb1[i]); xb1h[i] = (short)h; xb1l[i] = (short)f2bf(rb1[i] - bf2f(h));
        }

        float b1a[4], b2a[4], b1b[4], b2b[4];
        int   k1a[4], k1b[4];
#pragma unroll
        for (int j = 0; j < 4; ++j) {
            b1a[j] = 3.4e38f; b2a[j] = 3.4e38f; k1a[j] = 0;
            b1b[j] = 3.4e38f; b2b[j] = 3.4e38f; k1b[j] = 0;
        }

        const unsigned short* recs = cbi + (size_t)s * 131072;
        const float*          c2s  = c2 + s * K;

        short8 A0, A1, A2, A3, C0, C1, C2, C3;   // two prefetch banks
        float  ca, cb2;
        LOADTILE(A0, A1, A2, A3, ca,  tbeg);
        LOADTILE(C0, C1, C2, C3, cb2, tbeg + 1);

#pragma unroll 1
        for (int tau = tbeg; tau < tend; tau += 2) {
            // ---- bank A: tile tau ----
            {
                short8 bh0 = A0, bh1 = A1, bl0 = A2, bl1 = A3;
                float  c2v = ca;
                if (tau + 2 < tend) LOADTILE(A0, A1, A2, A3, ca, tau + 2);
                float4v aa = {0.f,0.f,0.f,0.f}, ab = {0.f,0.f,0.f,0.f};
                aa = __builtin_amdgcn_mfma_f32_16x16x32_bf16(xa0h, bh0, aa, 0,0,0);
                aa = __builtin_amdgcn_mfma_f32_16x16x32_bf16(xa0l, bh0, aa, 0,0,0);
                aa = __builtin_amdgcn_mfma_f32_16x16x32_bf16(xa0h, bl0, aa, 0,0,0);
                aa = __builtin_amdgcn_mfma_f32_16x16x32_bf16(xa1h, bh1, aa, 0,0,0);
                aa = __builtin_amdgcn_mfma_f32_16x16x32_bf16(xa1l, bh1, aa, 0,0,0);
                aa = __builtin_amdgcn_mfma_f32_16x16x32_bf16(xa1h, bl1, aa, 0,0,0);
                ab = __builtin_amdgcn_mfma_f32_16x16x32_bf16(xb0h, bh0, ab, 0,0,0);
                ab = __builtin_amdgcn_mfma_f32_16x16x32_bf16(xb0l, bh0, ab, 0,0,0);
                ab = __builtin_amdgcn_mfma_f32_16x16x32_bf16(xb0h, bl0, ab, 0,0,0);
                ab = __builtin_amdgcn_mfma_f32_16x16x32_bf16(xb1h, bh1, ab, 0,0,0);
                ab = __builtin_amdgcn_mfma_f32_16x16x32_bf16(xb1l, bh1, ab, 0,0,0);
                ab = __builtin_amdgcn_mfma_f32_16x16x32_bf16(xb1h, bl1, ab, 0,0,0);
                int ncol = tau * 16 + m;
#pragma unroll
                for (int j = 0; j < 4; ++j) {
                    float sa = fmaf(-2.f, aa[j], c2v);
                    b2a[j] = fminf(b2a[j], fmaxf(sa, b1a[j]));
                    k1a[j] = (sa < b1a[j]) ? ncol : k1a[j];
                    b1a[j] = fminf(sa, b1a[j]);
                    float sb = fmaf(-2.f, ab[j], c2v);
                    b2b[j] = fminf(b2b[j], fmaxf(sb, b1b[j]));
                    k1b[j] = (sb < b1b[j]) ? ncol : k1b[j];
                    b1b[j] = fminf(sb, b1b[j]);
                }
            }
            // ---- bank B: tile tau+1 ----
            {
                short8 bh0 = C0, bh1 = C1, bl0 = C2, bl1 = C3;
                float  c2v = cb2;
                if (tau + 3 < tend) LOADTILE(C0, C1, C2, C3, cb2, tau + 3);
                float4v aa = {0.f,0.f,0.f,0.f}, ab = {0.f,0.f,0.f,0.f};
                aa = __builtin_amdgcn_mfma_f32_16x16x32_bf16(xa0h, bh0, aa, 0,0,0);
                aa = __builtin_amdgcn_mfma_f32_16x16x32_bf16(xa0l, bh0, aa, 0,0,0);
                aa = __builtin_amdgcn_mfma_f32_16x16x32_bf16(xa0h, bl0, aa, 0,0,0);
                aa = __builtin_amdgcn_mfma_f32_16x16x32_bf16(xa1h, bh1, aa, 0,0,0);
                aa = __builtin_amdgcn_mfma_f32_16x16x32_bf16(xa1l, bh1, aa, 0,0,0);
                aa = __builtin_amdgcn_mfma_f32_16x16x32_bf16(xa1h, bl1, aa, 0,0,0);
                ab = __builtin_amdgcn_mfma_f32_16x16x32_bf16(xb0h, bh0, ab, 0,0,0);
                ab = __builtin_amdgcn_mfma_f32_16x16x32_bf16(xb0l, bh0, ab, 0,0,0);
                ab = __builtin_amdgcn_mfma_f32_16x16x32_bf16(xb0h, bl0, ab, 0,0,0);
                ab = __builtin_amdgcn_mfma_f32_16x16x32_bf16(xb1h, bh1, ab, 0,0,0);
                ab = __builtin_amdgcn_mfma_f32_16x16x32_bf16(xb1l, bh1, ab, 0,0,0);
                ab = __builtin_amdgcn_mfma_f32_16x16x32_bf16(xb1h, bl1, ab, 0,0,0);
                int ncol = (tau + 1) * 16 + m;
#pragma unroll
                for (int j = 0; j < 4; ++j) {
                    float sa = fmaf(-2.f, aa[j], c2v);
                    b2a[j] = fminf(b2a[j], fmaxf(sa, b1a[j]));
                    k1a[j] = (sa < b1a[j]) ? ncol : k1a[j];
                    b1a[j] = fminf(sa, b1a[j]);
                    float sb = fmaf(-2.f, ab[j], c2v);
                    b2b[j] = fminf(b2b[j], fmaxf(sb, b1b[j]));
                    k1b[j] = (sb < b1b[j]) ? ncol : k1b[j];
                    b1b[j] = fminf(sb, b1b[j]);
                }
            }
        }

        // ---- reduce across the 16 col-lanes (k-tie: lowest k) ----
#pragma unroll
        for (int off = 1; off < 16; off <<= 1) {
#pragma unroll
            for (int j = 0; j < 4; ++j) {
                float o1 = __shfl_xor(b1a[j], off); int ok = __shfl_xor(k1a[j], off);
                float o2 = __shfl_xor(b2a[j], off);
                float n2 = fminf(fminf(b2a[j], o2), fmaxf(b1a[j], o1));
                bool tk = (o1 < b1a[j]) || (o1 == b1a[j] && ok < k1a[j]);
                k1a[j] = tk ? ok : k1a[j]; b1a[j] = fminf(b1a[j], o1); b2a[j] = n2;
                o1 = __shfl_xor(b1b[j], off); ok = __shfl_xor(k1b[j], off);
                o2 = __shfl_xor(b2b[j], off);
                n2 = fminf(fminf(b2b[j], o2), fmaxf(b1b[j], o1));
                tk = (o1 < b1b[j]) || (o1 == b1b[j] && ok < k1b[j]);
                k1b[j] = tk ? ok : k1b[j]; b1b[j] = fminf(b1b[j], o1); b2b[j] = n2;
            }
        }

        // ---- cross-wave top-2 merge via LDS: ALL 16 rows per set.
        //      Group leader (m==0: lanes 0/16/32/48) writes rows q*4+j. ----
        if (m == 0) {
#pragma unroll
            for (int j = 0; j < 4; ++j) {
                lds_b1[wave][0][q*4+j] = b1a[j]; lds_b2[wave][0][q*4+j] = b2a[j]; lds_k[wave][0][q*4+j] = k1a[j];
                lds_b1[wave][1][q*4+j] = b1b[j]; lds_b2[wave][1][q*4+j] = b2b[j]; lds_k[wave][1][q*4+j] = k1b[j];
            }
        }
        __syncthreads();
        {
            int ow = 1 - wave;
#pragma unroll
            for (int j = 0; j < 4; ++j) {
                float o1 = lds_b1[ow][0][q*4+j]; float o2 = lds_b2[ow][0][q*4+j]; int ok = lds_k[ow][0][q*4+j];
                float n2 = fminf(fminf(b2a[j], o2), fmaxf(b1a[j], o1));
                bool tk = (o1 < b1a[j]) || (o1 == b1a[j] && ok < k1a[j]);
                k1a[j] = tk ? ok : k1a[j]; b1a[j] = fminf(b1a[j], o1); b2a[j] = n2;
                o1 = lds_b1[ow][1][q*4+j]; o2 = lds_b2[ow][1][q*4+j]; ok = lds_k[ow][1][q*4+j];
                n2 = fminf(fminf(b2b[j], o2), fmaxf(b1b[j], o1));
                tk = (o1 < b1b[j]) || (o1 == b1b[j] && ok < k1b[j]);
                k1b[j] = tk ? ok : k1b[j]; b1b[j] = fminf(b1b[j], o1); b2b[j] = n2;
            }
        }
        __syncthreads();   // protect LDS slots before next stage's writes

        // ---- δ-rescue: exact fp32 rescan of ambiguous rows (rare; both
        //      waves run it redundantly — identical post-merge state) ----
        const float* cr0 = cbf + (size_t)s * 65536;
#define RESCUE(b1X, b2X, k1X, R0, R1)                                         \
        for (int j = 0; j < 4; ++j) {                                         \
            unsigned long long mask = __ballot(b2X[j] - b1X[j] < DELTA);      \
            while (mask) {                                                    \
                int lq = (int)(__builtin_ctzll(mask)) >> 4;                   \
                mask &= ~(0xFFFFULL << (lq * 16));                            \
                int mrow = lq * 4 + j;                                        \
                float bd = 3.4e38f; int bk = 0;                               \
                for (int cc = 0; cc < 16; ++cc) {                             \
                    int n = cc * 64 + lane;                                   \
                    const float* crow = cr0 + (size_t)n * 64;                 \
                    float dot = 0.f;                                          \
                    for (int p = 0; p < 4; ++p) {                             \
                        for (int i = 0; i < 8; ++i)                           \
                            dot = fmaf(__shfl(R0[i], mrow + 16*p), crow[p*8+i], dot); \
                        for (int i = 0; i < 8; ++i)                           \
                            dot = fmaf(__shfl(R1[i], mrow + 16*p), crow[32+p*8+i], dot); \
                    }                                                         \
                    float sc = c2s[n] - 2.f * dot;                            \
                    if (sc < bd) { bd = sc; bk = n; }                         \
                }                                                             \
                for (int off = 1; off < 64; off <<= 1) {                      \
                    float ob = __shfl_xor(bd, off); int ok = __shfl_xor(bk, off); \
                    bool tk = (ob < bd) || (ob == bd && ok < bk);             \
                    bk = tk ? ok : bk; bd = fminf(bd, ob);                    \
                }                                                             \
                if (q == lq) k1X[j] = bk;                                     \
            }                                                                 \
        }
        RESCUE(b1a, b2a, k1a, ra0, ra1)
        RESCUE(b1b, b2b, k1b, rb0, rb1)
#undef RESCUE

        // ---- transpose winners to per-lane rows (row = m), convergent ----
        int mm = m & 3, src = (m >> 2) * 16;
        int wa0 = __shfl(k1a[0], src), wa1 = __shfl(k1a[1], src);
        int wa2 = __shfl(k1a[2], src), wa3 = __shfl(k1a[3], src);
        int bka = (mm == 0) ? wa0 : (mm == 1) ? wa1 : (mm == 2) ? wa2 : wa3;
        int wb0 = __shfl(k1b[0], src), wb1 = __shfl(k1b[1], src);
        int wb2 = __shfl(k1b[2], src), wb3 = __shfl(k1b[3], src);
        int bkb = (mm == 0) ? wb0 : (mm == 1) ? wb1 : (mm == 2) ? wb2 : wb3;

        // ---- fp32 residual update (both waves, identical) ----
        const float* qa = cbf + (size_t)s * 65536 + (size_t)bka * 64;
        const float* qb = cbf + (size_t)s * 65536 + (size_t)bkb * 64;
#pragma unroll
        for (int i = 0; i < 8; ++i) {
            ra0[i] -= qa[q*8+i];  ra1[i] -= qa[32+q*8+i];
            rb0[i] -= qb[q*8+i];  rb1[i] -= qb[32+q*8+i];
        }

        // ---- loss + histogram (wave 0 only) ----
        if (wave == 0) {
            float ls = 0.f;
#pragma unroll
            for (int i = 0; i < 8; ++i) {
                ls = fmaf(ra0[i], ra0[i], ls); ls = fmaf(ra1[i], ra1[i], ls);
                ls = fmaf(rb0[i], rb0[i], ls); ls = fmaf(rb1[i], rb1[i], ls);
            }
#pragma unroll
            for (int off = 1; off < 64; off <<= 1) ls += __shfl_xor(ls, off);
            if (lane == 0) lossp[s * NB + wid] = ls;
            if (q == 0) {
                atomicAdd(&cnt[s * K + bka], 1u);   // vector vbase+m
                atomicAdd(&cnt[s * K + bkb], 1u);   // vector vbase+16+m
            }
        }
    }
#undef LOADTILE

    // ---- epilogue: zq = z - r_final (wave 0 only) ----
    if (wave == 0) {
#pragma unroll
        for (int i = 0; i < 8; ++i) {
            size_t a0 = zrow + ((size_t)(q*8+i)    << 12) + ta;
            size_t a1 = zrow + ((size_t)(32+q*8+i) << 12) + ta;
            zq[a0] = z[a0] - ra0[i];
            zq[a1] = z[a1] - ra1[i];
            size_t a2 = zrow + ((size_t)(q*8+i)    << 12) + tb;
            size_t a3 = zrow + ((size_t)(32+q*8+i) << 12) + tb;
            zq[a2] = z[a2] - rb0[i];
            zq[a3] = z[a3] - rb1[i];
        }
    }
}

// ---------------------------------------------------------------------------
// Finalize: losses (mean of summed wave partials) + perplexities
// ---------------------------------------------------------------------------
__global__ void rvq_finalize(const float* __restrict__ lossp,
                             const unsigned* __restrict__ cnt,
                             float* __restrict__ out_loss,
                             float* __restrict__ out_perp) {
    const int s   = blockIdx.x;
    const int tid = threadIdx.x;
    float ent = 0.f, lsum = 0.f;
    for (int i = tid; i < K; i += 256) {
        float p = (float)cnt[s * K + i] * (1.0f / 65536.0f);
        ent += p * logf(p + EPSQ);
    }
    for (int i = tid; i < NB; i += 256) lsum += lossp[s * NB + i];
    __shared__ float redE[4], redL[4];
#pragma unroll
    for (int off = 32; off > 0; off >>= 1) {
        ent  += __shfl_down(ent, off);
        lsum += __shfl_down(lsum, off);
    }
    if ((tid & 63) == 0) { redE[tid >> 6] = ent; redL[tid >> 6] = lsum; }
    __syncthreads();
    if (tid == 0) {
        float te = redE[0] + redE[1] + redE[2] + redE[3];
        float tl = redL[0] + redL[1] + redL[2] + redL[3];
        out_perp[s] = expf(-te);
        out_loss[s] = tl * (1.0f / NELEM);
    }
}

// ---------------------------------------------------------------------------
extern "C" void kernel_launch(void* const* d_in, const int* in_sizes, int n_in,
                              void* d_out, int out_size, void* d_ws, size_t ws_size,
                              hipStream_t stream) {
    const float* z  = (const float*)d_in[0];
    const float* cb = (const float*)d_in[1];

    float* zq       = (float*)d_out;
    float* out_loss = zq + 4194304;
    float* out_perp = out_loss + 8;

    // ws: cbi 2 MB | c2 32 KB | cnt 32 KB | lossp 64 KB
    char* ws = (char*)d_ws;
    unsigned short* cbi = (unsigned short*)(ws);
    float*    c2    = (float*)(ws + 2097152);
    unsigned* cnt   = (unsigned*)(ws + 2129920);
    float*    lossp = (float*)(ws + 2162688);

    hipLaunchKernelGGL(rvq_prep,     dim3(128),  dim3(256), 0, stream, cb, cbi, c2, cnt);
    hipLaunchKernelGGL(rvq_main,     dim3(NB),   dim3(128), 0, stream, z, cb, cbi, c2, zq, lossp, cnt);
    hipLaunchKernelGGL(rvq_finalize, dim3(S),    dim3(256), 0, stream, lossp, cnt, out_loss, out_perp);
}

// Round 12
// 559.877 us; speedup vs baseline: 2.0063x; 2.0063x over previous
//
#include <hip/hip_runtime.h>

// RVQ: z [16,64,4096] f32, codebooks [8,1024,64] f32 -> zq + 8 losses + 8 perplexities
#define S      8
#define K      1024
#define D      64
#define NVEC   65536
#define NB     2048      // blocks; 32 vectors each, 2 waves split the k-range
#define NELEM  4194304.0f
#define EPSQ   1e-10f
#define DELTA  0.005f    // exact-rescan margin >> split-bf16 score error (~2e-3 worst)

typedef __attribute__((ext_vector_type(8))) short  short8;   // 8 bf16
typedef __attribute__((ext_vector_type(4))) float  float4v;  // MFMA acc

static __device__ inline unsigned short f2bf(float f) {
    unsigned int u = __float_as_uint(f);
    u = (u + 0x7FFFu + ((u >> 16) & 1u)) >> 16;
    return (unsigned short)u;
}
static __device__ inline float bf2f(unsigned short h) {
    return __uint_as_float(((unsigned int)h) << 16);
}

// ---------------------------------------------------------------------------
// Prep: (a) c2 + zero cnt; (b) interleave codebook into B-fragment streaming
// records: per (stage, tile of 16 cw) a 4 KB record of 4 segments
// [h0hi][h1hi][h0lo][h1lo]; slot l holds cw=tile*16+(l&15),
// dims h*32+(l>>4)*8+0..7 as bf16x8 -> main kernel reads base+l*16 coalesced.
// ---------------------------------------------------------------------------
__global__ void rvq_prep(const float* __restrict__ cb,
                         unsigned short* __restrict__ cbi,
                         float* __restrict__ c2, unsigned* __restrict__ cnt) {
    int i = blockIdx.x * blockDim.x + threadIdx.x;   // 0..32767
    if (i < S * K) {   // c2 + cnt zero
        const float* row = cb + (size_t)i * D;
        float a0 = 0.f, a1 = 0.f, a2 = 0.f, a3 = 0.f;
#pragma unroll
        for (int d = 0; d < D; d += 4) {
            a0 = fmaf(row[d+0], row[d+0], a0);
            a1 = fmaf(row[d+1], row[d+1], a1);
            a2 = fmaf(row[d+2], row[d+2], a2);
            a3 = fmaf(row[d+3], row[d+3], a3);
        }
        c2[i] = (a0 + a1) + (a2 + a3);
        cnt[i] = 0u;
    }
    // interleave: i = s*4096 + tau*64 + l
    int s  = i >> 12;
    int tau = (i >> 6) & 63;
    int l  = i & 63;
    int m  = l & 15, qq = l >> 4;
    const float* row = cb + (size_t)(s * K + tau * 16 + m) * D;
    short8 h0h, h0l, h1h, h1l;
#pragma unroll
    for (int e = 0; e < 8; ++e) {
        float x = row[qq * 8 + e];
        unsigned short h = f2bf(x);
        h0h[e] = (short)h; h0l[e] = (short)f2bf(x - bf2f(h));
        float y = row[32 + qq * 8 + e];
        unsigned short g = f2bf(y);
        h1h[e] = (short)g; h1l[e] = (short)f2bf(y - bf2f(g));
    }
    unsigned short* rec = cbi + (size_t)(s * 64 + tau) * 2048 + l * 8;
    *(short8*)(rec +    0) = h0h;
    *(short8*)(rec +  512) = h1h;
    *(short8*)(rec + 1024) = h0l;
    *(short8*)(rec + 1536) = h1l;
}

// ---------------------------------------------------------------------------
// Main: block = 2 waves x 32 vectors (shared). Wave w scans k-tiles
// [32w, 32w+32); cross-wave top-2 merge (all 16 rows/set) via LDS.
// R11 lesson: __launch_bounds__(_,3) makes the backend target 6 waves/EU
// (84 VGPRs) -> r-state + prefetch banks spilled to scratch (1.14 GB of
// WRITE traffic, 2.5x regression). (_,2) targets the 128-VGPR budget the
// wave actually needs (R5/R9 precedent: 116/124, no spill) while the
// 4096-wave grid still fills 4 waves/SIMD.
// ---------------------------------------------------------------------------
__global__ __launch_bounds__(128, 2)
void rvq_main(const float* __restrict__ z, const float* __restrict__ cbf,
              const unsigned short* __restrict__ cbi,
              const float* __restrict__ c2, float* __restrict__ zq,
              float* __restrict__ lossp, unsigned* __restrict__ cnt) {
    __shared__ float lds_b1[2][2][16];
    __shared__ float lds_b2[2][2][16];
    __shared__ int   lds_k [2][2][16];

    const int tid  = threadIdx.x;
    const int lane = tid & 63;
    const int wave = tid >> 6;
    const int m    = lane & 15;
    const int q    = lane >> 4;
    const int wid  = blockIdx.x;
    const int vbase = wid * 32;
    const int b    = vbase >> 12;
    const int ta   = (vbase & 4095) + m;        // set-a t
    const int tb   = ta + 16;                   // set-b t
    const size_t zrow = ((size_t)(b * 64)) << 12;
    const int tbeg = wave * 32;                 // this wave's k-tile range
    const int tend = tbeg + 32;

    float ra0[8], ra1[8], rb0[8], rb1[8];
#pragma unroll
    for (int i = 0; i < 8; ++i) {
        ra0[i] = z[zrow + ((size_t)(q*8+i)    << 12) + ta];
        ra1[i] = z[zrow + ((size_t)(32+q*8+i) << 12) + ta];
        rb0[i] = z[zrow + ((size_t)(q*8+i)    << 12) + tb];
        rb1[i] = z[zrow + ((size_t)(32+q*8+i) << 12) + tb];
    }

#define LOADTILE(B0v, B1v, B2v, B3v, CCv, tt) {                              \
        const unsigned short* p_ = recs + (size_t)(tt) * 2048 + lane * 8;    \
        B0v = *(const short8*)(p_);                                          \
        B1v = *(const short8*)(p_ + 512);                                    \
        B2v = *(const short8*)(p_ + 1024);                                   \
        B3v = *(const short8*)(p_ + 1536);                                   \
        CCv = c2s[(tt) * 16 + m]; }

#pragma unroll 1
    for (int s = 0; s < S; ++s) {
        // split residuals to bf16 hi/lo A-fragments
        short8 xa0h, xa0l, xa1h, xa1l, xb0h, xb0l, xb1h, xb1l;
#pragma unroll
        for (int i = 0; i < 8; ++i) {
            unsigned short h;
            h = f2bf(ra0[i]); xa0h[i] = (short)h; xa0l[i] = (short)f2bf(ra0[i] - bf2f(h));
            h = f2bf(ra1[i]); xa1h[i] = (short)h; xa1l[i] = (short)f2bf(ra1[i] - bf2f(h));
            h = f2bf(rb0[i]); xb0h[i] = (short)h; xb0l[i] = (short)f2bf(rb0[i] - bf2f(h));
            h = f2bf(rb1[i]); xb1h[i] = (short)h; xb1l[i] = (short)f2bf(rb1[i] - bf2f(h));
        }

        float b1a[4], b2a[4], b1b[4], b2b[4];
        int   k1a[4], k1b[4];
#pragma unroll
        for (int j = 0; j < 4; ++j) {
            b1a[j] = 3.4e38f; b2a[j] = 3.4e38f; k1a[j] = 0;
            b1b[j] = 3.4e38f; b2b[j] = 3.4e38f; k1b[j] = 0;
        }

        const unsigned short* recs = cbi + (size_t)s * 131072;
        const float*          c2s  = c2 + s * K;

        short8 A0, A1, A2, A3, C0, C1, C2, C3;   // two prefetch banks
        float  ca, cb2;
        LOADTILE(A0, A1, A2, A3, ca,  tbeg);
        LOADTILE(C0, C1, C2, C3, cb2, tbeg + 1);

#pragma unroll 1
        for (int tau = tbeg; tau < tend; tau += 2) {
            // ---- bank A: tile tau ----
            {
                short8 bh0 = A0, bh1 = A1, bl0 = A2, bl1 = A3;
                float  c2v = ca;
                if (tau + 2 < tend) LOADTILE(A0, A1, A2, A3, ca, tau + 2);
                float4v aa = {0.f,0.f,0.f,0.f}, ab = {0.f,0.f,0.f,0.f};
                aa = __builtin_amdgcn_mfma_f32_16x16x32_bf16(xa0h, bh0, aa, 0,0,0);
                aa = __builtin_amdgcn_mfma_f32_16x16x32_bf16(xa0l, bh0, aa, 0,0,0);
                aa = __builtin_amdgcn_mfma_f32_16x16x32_bf16(xa0h, bl0, aa, 0,0,0);
                aa = __builtin_amdgcn_mfma_f32_16x16x32_bf16(xa1h, bh1, aa, 0,0,0);
                aa = __builtin_amdgcn_mfma_f32_16x16x32_bf16(xa1l, bh1, aa, 0,0,0);
                aa = __builtin_amdgcn_mfma_f32_16x16x32_bf16(xa1h, bl1, aa, 0,0,0);
                ab = __builtin_amdgcn_mfma_f32_16x16x32_bf16(xb0h, bh0, ab, 0,0,0);
                ab = __builtin_amdgcn_mfma_f32_16x16x32_bf16(xb0l, bh0, ab, 0,0,0);
                ab = __builtin_amdgcn_mfma_f32_16x16x32_bf16(xb0h, bl0, ab, 0,0,0);
                ab = __builtin_amdgcn_mfma_f32_16x16x32_bf16(xb1h, bh1, ab, 0,0,0);
                ab = __builtin_amdgcn_mfma_f32_16x16x32_bf16(xb1l, bh1, ab, 0,0,0);
                ab = __builtin_amdgcn_mfma_f32_16x16x32_bf16(xb1h, bl1, ab, 0,0,0);
                int ncol = tau * 16 + m;
#pragma unroll
                for (int j = 0; j < 4; ++j) {
                    float sa = fmaf(-2.f, aa[j], c2v);
                    b2a[j] = fminf(b2a[j], fmaxf(sa, b1a[j]));
                    k1a[j] = (sa < b1a[j]) ? ncol : k1a[j];
                    b1a[j] = fminf(sa, b1a[j]);
                    float sb = fmaf(-2.f, ab[j], c2v);
                    b2b[j] = fminf(b2b[j], fmaxf(sb, b1b[j]));
                    k1b[j] = (sb < b1b[j]) ? ncol : k1b[j];
                    b1b[j] = fminf(sb, b1b[j]);
                }
            }
            // ---- bank B: tile tau+1 ----
            {
                short8 bh0 = C0, bh1 = C1, bl0 = C2, bl1 = C3;
                float  c2v = cb2;
                if (tau + 3 < tend) LOADTILE(C0, C1, C2, C3, cb2, tau + 3);
                float4v aa = {0.f,0.f,0.f,0.f}, ab = {0.f,0.f,0.f,0.f};
                aa = __builtin_amdgcn_mfma_f32_16x16x32_bf16(xa0h, bh0, aa, 0,0,0);
                aa = __builtin_amdgcn_mfma_f32_16x16x32_bf16(xa0l, bh0, aa, 0,0,0);
                aa = __builtin_amdgcn_mfma_f32_16x16x32_bf16(xa0h, bl0, aa, 0,0,0);
                aa = __builtin_amdgcn_mfma_f32_16x16x32_bf16(xa1h, bh1, aa, 0,0,0);
                aa = __builtin_amdgcn_mfma_f32_16x16x32_bf16(xa1l, bh1, aa, 0,0,0);
                aa = __builtin_amdgcn_mfma_f32_16x16x32_bf16(xa1h, bl1, aa, 0,0,0);
                ab = __builtin_amdgcn_mfma_f32_16x16x32_bf16(xb0h, bh0, ab, 0,0,0);
                ab = __builtin_amdgcn_mfma_f32_16x16x32_bf16(xb0l, bh0, ab, 0,0,0);
                ab = __builtin_amdgcn_mfma_f32_16x16x32_bf16(xb0h, bl0, ab, 0,0,0);
                ab = __builtin_amdgcn_mfma_f32_16x16x32_bf16(xb1h, bh1, ab, 0,0,0);
                ab = __builtin_amdgcn_mfma_f32_16x16x32_bf16(xb1l, bh1, ab, 0,0,0);
                ab = __builtin_amdgcn_mfma_f32_16x16x32_bf16(xb1h, bl1, ab, 0,0,0);
                int ncol = (tau + 1) * 16 + m;
#pragma unroll
                for (int j = 0; j < 4; ++j) {
                    float sa = fmaf(-2.f, aa[j], c2v);
                    b2a[j] = fminf(b2a[j], fmaxf(sa, b1a[j]));
                    k1a[j] = (sa < b1a[j]) ? ncol : k1a[j];
                    b1a[j] = fminf(sa, b1a[j]);
                    float sb = fmaf(-2.f, ab[j], c2v);
                    b2b[j] = fminf(b2b[j], fmaxf(sb, b1b[j]));
                    k1b[j] = (sb < b1b[j]) ? ncol : k1b[j];
                    b1b[j] = fminf(sb, b1b[j]);
                }
            }
        }

        // ---- reduce across the 16 col-lanes (k-tie: lowest k) ----
#pragma unroll
        for (int off = 1; off < 16; off <<= 1) {
#pragma unroll
            for (int j = 0; j < 4; ++j) {
                float o1 = __shfl_xor(b1a[j], off); int ok = __shfl_xor(k1a[j], off);
                float o2 = __shfl_xor(b2a[j], off);
                float n2 = fminf(fminf(b2a[j], o2), fmaxf(b1a[j], o1));
                bool tk = (o1 < b1a[j]) || (o1 == b1a[j] && ok < k1a[j]);
                k1a[j] = tk ? ok : k1a[j]; b1a[j] = fminf(b1a[j], o1); b2a[j] = n2;
                o1 = __shfl_xor(b1b[j], off); ok = __shfl_xor(k1b[j], off);
                o2 = __shfl_xor(b2b[j], off);
                n2 = fminf(fminf(b2b[j], o2), fmaxf(b1b[j], o1));
                tk = (o1 < b1b[j]) || (o1 == b1b[j] && ok < k1b[j]);
                k1b[j] = tk ? ok : k1b[j]; b1b[j] = fminf(b1b[j], o1); b2b[j] = n2;
            }
        }

        // ---- cross-wave top-2 merge via LDS: ALL 16 rows per set.
        //      Group leader (m==0: lanes 0/16/32/48) writes rows q*4+j. ----
        if (m == 0) {
#pragma unroll
            for (int j = 0; j < 4; ++j) {
                lds_b1[wave][0][q*4+j] = b1a[j]; lds_b2[wave][0][q*4+j] = b2a[j]; lds_k[wave][0][q*4+j] = k1a[j];
                lds_b1[wave][1][q*4+j] = b1b[j]; lds_b2[wave][1][q*4+j] = b2b[j]; lds_k[wave][1][q*4+j] = k1b[j];
            }
        }
        __syncthreads();
        {
            int ow = 1 - wave;
#pragma unroll
            for (int j = 0; j < 4; ++j) {
                float o1 = lds_b1[ow][0][q*4+j]; float o2 = lds_b2[ow][0][q*4+j]; int ok = lds_k[ow][0][q*4+j];
                float n2 = fminf(fminf(b2a[j], o2), fmaxf(b1a[j], o1));
                bool tk = (o1 < b1a[j]) || (o1 == b1a[j] && ok < k1a[j]);
                k1a[j] = tk ? ok : k1a[j]; b1a[j] = fminf(b1a[j], o1); b2a[j] = n2;
                o1 = lds_b1[ow][1][q*4+j]; o2 = lds_b2[ow][1][q*4+j]; ok = lds_k[ow][1][q*4+j];
                n2 = fminf(fminf(b2b[j], o2), fmaxf(b1b[j], o1));
                tk = (o1 < b1b[j]) || (o1 == b1b[j] && ok < k1b[j]);
                k1b[j] = tk ? ok : k1b[j]; b1b[j] = fminf(b1b[j], o1); b2b[j] = n2;
            }
        }
        __syncthreads();   // protect LDS slots before next stage's writes

        // ---- δ-rescue: exact fp32 rescan of ambiguous rows (rare; both
        //      waves run it redundantly — identical post-merge state) ----
        const float* cr0 = cbf + (size_t)s * 65536;
#define RESCUE(b1X, b2X, k1X, R0, R1)                                         \
        for (int j = 0; j < 4; ++j) {                                         \
            unsigned long long mask = __ballot(b2X[j] - b1X[j] < DELTA);      \
            while (mask) {                                                    \
                int lq = (int)(__builtin_ctzll(mask)) >> 4;                   \
                mask &= ~(0xFFFFULL << (lq * 16));                            \
                int mrow = lq * 4 + j;                                        \
                float bd = 3.4e38f; int bk = 0;                               \
                for (int cc = 0; cc < 16; ++cc) {                             \
                    int n = cc * 64 + lane;                                   \
                    const float* crow = cr0 + (size_t)n * 64;                 \
                    float dot = 0.f;                                          \
                    for (int p = 0; p < 4; ++p) {                             \
                        for (int i = 0; i < 8; ++i)                           \
                            dot = fmaf(__shfl(R0[i], mrow + 16*p), crow[p*8+i], dot); \
                        for (int i = 0; i < 8; ++i)                           \
                            dot = fmaf(__shfl(R1[i], mrow + 16*p), crow[32+p*8+i], dot); \
                    }                                                         \
                    float sc = c2s[n] - 2.f * dot;                            \
                    if (sc < bd) { bd = sc; bk = n; }                         \
                }                                                             \
                for (int off = 1; off < 64; off <<= 1) {                      \
                    float ob = __shfl_xor(bd, off); int ok = __shfl_xor(bk, off); \
                    bool tk = (ob < bd) || (ob == bd && ok < bk);             \
                    bk = tk ? ok : bk; bd = fminf(bd, ob);                    \
                }                                                             \
                if (q == lq) k1X[j] = bk;                                     \
            }                                                                 \
        }
        RESCUE(b1a, b2a, k1a, ra0, ra1)
        RESCUE(b1b, b2b, k1b, rb0, rb1)
#undef RESCUE

        // ---- transpose winners to per-lane rows (row = m), convergent ----
        int mm = m & 3, src = (m >> 2) * 16;
        int wa0 = __shfl(k1a[0], src), wa1 = __shfl(k1a[1], src);
        int wa2 = __shfl(k1a[2], src), wa3 = __shfl(k1a[3], src);
        int bka = (mm == 0) ? wa0 : (mm == 1) ? wa1 : (mm == 2) ? wa2 : wa3;
        int wb0 = __shfl(k1b[0], src), wb1 = __shfl(k1b[1], src);
        int wb2 = __shfl(k1b[2], src), wb3 = __shfl(k1b[3], src);
        int bkb = (mm == 0) ? wb0 : (mm == 1) ? wb1 : (mm == 2) ? wb2 : wb3;

        // ---- fp32 residual update (both waves, identical) ----
        const float* qa = cbf + (size_t)s * 65536 + (size_t)bka * 64;
        const float* qb = cbf + (size_t)s * 65536 + (size_t)bkb * 64;
#pragma unroll
        for (int i = 0; i < 8; ++i) {
            ra0[i] -= qa[q*8+i];  ra1[i] -= qa[32+q*8+i];
            rb0[i] -= qb[q*8+i];  rb1[i] -= qb[32+q*8+i];
        }

        // ---- loss + histogram (wave 0 only) ----
        if (wave == 0) {
            float ls = 0.f;
#pragma unroll
            for (int i = 0; i < 8; ++i) {
                ls = fmaf(ra0[i], ra0[i], ls); ls = fmaf(ra1[i], ra1[i], ls);
                ls = fmaf(rb0[i], rb0[i], ls); ls = fmaf(rb1[i], rb1[i], ls);
            }
#pragma unroll
            for (int off = 1; off < 64; off <<= 1) ls += __shfl_xor(ls, off);
            if (lane == 0) lossp[s * NB + wid] = ls;
            if (q == 0) {
                atomicAdd(&cnt[s * K + bka], 1u);   // vector vbase+m
                atomicAdd(&cnt[s * K + bkb], 1u);   // vector vbase+16+m
            }
        }
    }
#undef LOADTILE

    // ---- epilogue: zq = z - r_final (wave 0 only) ----
    if (wave == 0) {
#pragma unroll
        for (int i = 0; i < 8; ++i) {
            size_t a0 = zrow + ((size_t)(q*8+i)    << 12) + ta;
            size_t a1 = zrow + ((size_t)(32+q*8+i) << 12) + ta;
            zq[a0] = z[a0] - ra0[i];
            zq[a1] = z[a1] - ra1[i];
            size_t a2 = zrow + ((size_t)(q*8+i)    << 12) + tb;
            size_t a3 = zrow + ((size_t)(32+q*8+i) << 12) + tb;
            zq[a2] = z[a2] - rb0[i];
            zq[a3] = z[a3] - rb1[i];
        }
    }
}

// ---------------------------------------------------------------------------
// Finalize: losses (mean of summed wave partials) + perplexities
// ---------------------------------------------------------------------------
__global__ void rvq_finalize(const float* __restrict__ lossp,
                             const unsigned* __restrict__ cnt,
                             float* __restrict__ out_loss,
                             float* __restrict__ out_perp) {
    const int s   = blockIdx.x;
    const int tid = threadIdx.x;
    float ent = 0.f, lsum = 0.f;
    for (int i = tid; i < K; i += 256) {
        float p = (float)cnt[s * K + i] * (1.0f / 65536.0f);
        ent += p * logf(p + EPSQ);
    }
    for (int i = tid; i < NB; i += 256) lsum += lossp[s * NB + i];
    __shared__ float redE[4], redL[4];
#pragma unroll
    for (int off = 32; off > 0; off >>= 1) {
        ent  += __shfl_down(ent, off);
        lsum += __shfl_down(lsum, off);
    }
    if ((tid & 63) == 0) { redE[tid >> 6] = ent; redL[tid >> 6] = lsum; }
    __syncthreads();
    if (tid == 0) {
        float te = redE[0] + redE[1] + redE[2] + redE[3];
        float tl = redL[0] + redL[1] + redL[2] + redL[3];
        out_perp[s] = expf(-te);
        out_loss[s] = tl * (1.0f / NELEM);
    }
}

// ---------------------------------------------------------------------------
extern "C" void kernel_launch(void* const* d_in, const int* in_sizes, int n_in,
                              void* d_out, int out_size, void* d_ws, size_t ws_size,
                              hipStream_t stream) {
    const float* z  = (const float*)d_in[0];
    const float* cb = (const float*)d_in[1];

    float* zq       = (float*)d_out;
    float* out_loss = zq + 4194304;
    float* out_perp = out_loss + 8;

    // ws: cbi 2 MB | c2 32 KB | cnt 32 KB | lossp 64 KB
    char* ws = (char*)d_ws;
    unsigned short* cbi = (unsigned short*)(ws);
    float*    c2    = (float*)(ws + 2097152);
    unsigned* cnt   = (unsigned*)(ws + 2129920);
    float*    lossp = (float*)(ws + 2162688);

    hipLaunchKernelGGL(rvq_prep,     dim3(128),  dim3(256), 0, stream, cb, cbi, c2, cnt);
    hipLaunchKernelGGL(rvq_main,     dim3(NB),   dim3(128), 0, stream, z, cb, cbi, c2, zq, lossp, cnt);
    hipLaunchKernelGGL(rvq_finalize, dim3(S),    dim3(256), 0, stream, lossp, cnt, out_loss, out_perp);
}

// Round 13
// 476.933 us; speedup vs baseline: 2.3552x; 1.1739x over previous
//
#include <hip/hip_runtime.h>

// RVQ: z [16,64,4096] f32, codebooks [8,1024,64] f32 -> zq + 8 losses + 8 perplexities
#define S      8
#define K      1024
#define D      64
#define NVEC   65536
#define NW     2048      // single-wave blocks, 32 vectors each (R9 structure)
#define NELEM  4194304.0f
#define EPSQ   1e-10f
// 4-term split-bf16 score error: typ ~2e-4, conservative worst ~1e-3 on a
// score difference. DELTA=2e-3 keeps 2x margin; rescue rate ~2.5x lower
// than R9's 5e-3 (rate is linear in DELTA — measured R6->R7).
#define DELTA  0.002f

typedef __attribute__((ext_vector_type(8))) short  short8;   // 8 bf16
typedef __attribute__((ext_vector_type(4))) float  float4v;  // MFMA acc

static __device__ inline unsigned short f2bf(float f) {
    unsigned int u = __float_as_uint(f);
    u = (u + 0x7FFFu + ((u >> 16) & 1u)) >> 16;
    return (unsigned short)u;
}
static __device__ inline float bf2f(unsigned short h) {
    return __uint_as_float(((unsigned int)h) << 16);
}

// ---------------------------------------------------------------------------
// Prep: (a) c2 + zero cnt; (b) interleave codebook into B-fragment streaming
// records: per (stage, tile of 16 cw) a 4 KB record of 4 segments
// [h0hi][h1hi][h0lo][h1lo]; slot l holds cw=tile*16+(l&15),
// dims h*32+(l>>4)*8+0..7 as bf16x8 -> main kernel reads base+l*16 coalesced.
// ---------------------------------------------------------------------------
__global__ void rvq_prep(const float* __restrict__ cb,
                         unsigned short* __restrict__ cbi,
                         float* __restrict__ c2, unsigned* __restrict__ cnt) {
    int i = blockIdx.x * blockDim.x + threadIdx.x;   // 0..32767
    if (i < S * K) {   // c2 + cnt zero
        const float* row = cb + (size_t)i * D;
        float a0 = 0.f, a1 = 0.f, a2 = 0.f, a3 = 0.f;
#pragma unroll
        for (int d = 0; d < D; d += 4) {
            a0 = fmaf(row[d+0], row[d+0], a0);
            a1 = fmaf(row[d+1], row[d+1], a1);
            a2 = fmaf(row[d+2], row[d+2], a2);
            a3 = fmaf(row[d+3], row[d+3], a3);
        }
        c2[i] = (a0 + a1) + (a2 + a3);
        cnt[i] = 0u;
    }
    // interleave: i = s*4096 + tau*64 + l
    int s  = i >> 12;
    int tau = (i >> 6) & 63;
    int l  = i & 63;
    int m  = l & 15, qq = l >> 4;
    const float* row = cb + (size_t)(s * K + tau * 16 + m) * D;
    short8 h0h, h0l, h1h, h1l;
#pragma unroll
    for (int e = 0; e < 8; ++e) {
        float x = row[qq * 8 + e];
        unsigned short h = f2bf(x);
        h0h[e] = (short)h; h0l[e] = (short)f2bf(x - bf2f(h));
        float y = row[32 + qq * 8 + e];
        unsigned short g = f2bf(y);
        h1h[e] = (short)g; h1l[e] = (short)f2bf(y - bf2f(g));
    }
    unsigned short* rec = cbi + (size_t)(s * 64 + tau) * 2048 + l * 8;
    *(short8*)(rec +    0) = h0h;
    *(short8*)(rec +  512) = h1h;
    *(short8*)(rec + 1024) = h0l;
    *(short8*)(rec + 1536) = h1l;
}

// ---------------------------------------------------------------------------
// Main (R9 structure: 1 wave/block, 32 vectors, no LDS, no barriers).
// R12 lesson: the R9 limiter was the 6-deep dependent MFMA chain per acc —
// MFMA busy measured 88us vs 25us throughput cost (3.5x = latency 17cyc /
// throughput 4.85cyc). Fix: 4 independent 2-deep chains per row-set
// (hi*hi, lo*hi, hi*lo, lo*lo), 8 chains per tile -> throughput-bound MFMA.
// The 4th term also shrinks score error ~10x -> DELTA 2e-3 (fewer rescues).
// ---------------------------------------------------------------------------
__global__ __launch_bounds__(64, 2)
void rvq_main(const float* __restrict__ z, const float* __restrict__ cbf,
              const unsigned short* __restrict__ cbi,
              const float* __restrict__ c2, float* __restrict__ zq,
              float* __restrict__ lossp, unsigned* __restrict__ cnt) {
    const int lane = threadIdx.x;
    const int m    = lane & 15;
    const int q    = lane >> 4;
    const int wid  = blockIdx.x;
    const int vbase = wid * 32;
    const int b    = vbase >> 12;
    const int ta   = (vbase & 4095) + m;        // set-a t
    const int tb   = ta + 16;                   // set-b t
    const size_t zrow = ((size_t)(b * 64)) << 12;

    float ra0[8], ra1[8], rb0[8], rb1[8];
#pragma unroll
    for (int i = 0; i < 8; ++i) {
        ra0[i] = z[zrow + ((size_t)(q*8+i)    << 12) + ta];
        ra1[i] = z[zrow + ((size_t)(32+q*8+i) << 12) + ta];
        rb0[i] = z[zrow + ((size_t)(q*8+i)    << 12) + tb];
        rb1[i] = z[zrow + ((size_t)(32+q*8+i) << 12) + tb];
    }

#define LOADTILE(B0v, B1v, B2v, B3v, CCv, tt) {                              \
        const unsigned short* p_ = recs + (size_t)(tt) * 2048 + lane * 8;    \
        B0v = *(const short8*)(p_);                                          \
        B1v = *(const short8*)(p_ + 512);                                    \
        B2v = *(const short8*)(p_ + 1024);                                   \
        B3v = *(const short8*)(p_ + 1536);                                   \
        CCv = c2s[(tt) * 16 + m]; }

// 16 MFMA per tile in 8 independent 2-deep chains; score = c2 - 2*sum(4 accs)
#define TILECOMP(bh0, bh1, bl0, bl1, c2v, ncol)                               \
    {                                                                         \
        float4v p1 = {0.f,0.f,0.f,0.f}, p2 = {0.f,0.f,0.f,0.f};               \
        float4v p3 = {0.f,0.f,0.f,0.f}, p4 = {0.f,0.f,0.f,0.f};               \
        float4v q1 = {0.f,0.f,0.f,0.f}, q2 = {0.f,0.f,0.f,0.f};               \
        float4v q3 = {0.f,0.f,0.f,0.f}, q4 = {0.f,0.f,0.f,0.f};               \
        p1 = __builtin_amdgcn_mfma_f32_16x16x32_bf16(xa0h, bh0, p1, 0,0,0);   \
        p2 = __builtin_amdgcn_mfma_f32_16x16x32_bf16(xa0l, bh0, p2, 0,0,0);   \
        p3 = __builtin_amdgcn_mfma_f32_16x16x32_bf16(xa0h, bl0, p3, 0,0,0);   \
        p4 = __builtin_amdgcn_mfma_f32_16x16x32_bf16(xa0l, bl0, p4, 0,0,0);   \
        q1 = __builtin_amdgcn_mfma_f32_16x16x32_bf16(xb0h, bh0, q1, 0,0,0);   \
        q2 = __builtin_amdgcn_mfma_f32_16x16x32_bf16(xb0l, bh0, q2, 0,0,0);   \
        q3 = __builtin_amdgcn_mfma_f32_16x16x32_bf16(xb0h, bl0, q3, 0,0,0);   \
        q4 = __builtin_amdgcn_mfma_f32_16x16x32_bf16(xb0l, bl0, q4, 0,0,0);   \
        p1 = __builtin_amdgcn_mfma_f32_16x16x32_bf16(xa1h, bh1, p1, 0,0,0);   \
        p2 = __builtin_amdgcn_mfma_f32_16x16x32_bf16(xa1l, bh1, p2, 0,0,0);   \
        p3 = __builtin_amdgcn_mfma_f32_16x16x32_bf16(xa1h, bl1, p3, 0,0,0);   \
        p4 = __builtin_amdgcn_mfma_f32_16x16x32_bf16(xa1l, bl1, p4, 0,0,0);   \
        q1 = __builtin_amdgcn_mfma_f32_16x16x32_bf16(xb1h, bh1, q1, 0,0,0);   \
        q2 = __builtin_amdgcn_mfma_f32_16x16x32_bf16(xb1l, bh1, q2, 0,0,0);   \
        q3 = __builtin_amdgcn_mfma_f32_16x16x32_bf16(xb1h, bl1, q3, 0,0,0);   \
        q4 = __builtin_amdgcn_mfma_f32_16x16x32_bf16(xb1l, bl1, q4, 0,0,0);   \
        _Pragma("unroll")                                                     \
        for (int j = 0; j < 4; ++j) {                                         \
            float sa = fmaf(-2.f, (p1[j]+p2[j]) + (p3[j]+p4[j]), c2v);        \
            b2a[j] = fminf(b2a[j], fmaxf(sa, b1a[j]));                        \
            k1a[j] = (sa < b1a[j]) ? (ncol) : k1a[j];                         \
            b1a[j] = fminf(sa, b1a[j]);                                       \
            float sb = fmaf(-2.f, (q1[j]+q2[j]) + (q3[j]+q4[j]), c2v);        \
            b2b[j] = fminf(b2b[j], fmaxf(sb, b1b[j]));                        \
            k1b[j] = (sb < b1b[j]) ? (ncol) : k1b[j];                         \
            b1b[j] = fminf(sb, b1b[j]);                                       \
        }                                                                     \
    }

#pragma unroll 1
    for (int s = 0; s < S; ++s) {
        // split residuals to bf16 hi/lo A-fragments
        short8 xa0h, xa0l, xa1h, xa1l, xb0h, xb0l, xb1h, xb1l;
#pragma unroll
        for (int i = 0; i < 8; ++i) {
            unsigned short h;
            h = f2bf(ra0[i]); xa0h[i] = (short)h; xa0l[i] = (short)f2bf(ra0[i] - bf2f(h));
            h = f2bf(ra1[i]); xa1h[i] = (short)h; xa1l[i] = (short)f2bf(ra1[i] - bf2f(h));
            h = f2bf(rb0[i]); xb0h[i] = (short)h; xb0l[i] = (short)f2bf(rb0[i] - bf2f(h));
            h = f2bf(rb1[i]); xb1h[i] = (short)h; xb1l[i] = (short)f2bf(rb1[i] - bf2f(h));
        }

        float b1a[4], b2a[4], b1b[4], b2b[4];
        int   k1a[4], k1b[4];
#pragma unroll
        for (int j = 0; j < 4; ++j) {
            b1a[j] = 3.4e38f; b2a[j] = 3.4e38f; k1a[j] = 0;
            b1b[j] = 3.4e38f; b2b[j] = 3.4e38f; k1b[j] = 0;
        }

        const unsigned short* recs = cbi + (size_t)s * 131072;
        const float*          c2s  = c2 + s * K;

        short8 A0, A1, A2, A3, C0, C1, C2, C3;   // two prefetch banks
        float  ca, cb2;
        LOADTILE(A0, A1, A2, A3, ca,  0);
        LOADTILE(C0, C1, C2, C3, cb2, 1);

#pragma unroll 1
        for (int tau = 0; tau < 64; tau += 2) {
            // ---- bank A: tile tau ----
            {
                short8 bh0 = A0, bh1 = A1, bl0 = A2, bl1 = A3;
                float  c2v = ca;
                if (tau + 2 < 64) LOADTILE(A0, A1, A2, A3, ca, tau + 2);
                TILECOMP(bh0, bh1, bl0, bl1, c2v, tau * 16 + m)
            }
            // ---- bank B: tile tau+1 ----
            {
                short8 bh0 = C0, bh1 = C1, bl0 = C2, bl1 = C3;
                float  c2v = cb2;
                if (tau + 3 < 64) LOADTILE(C0, C1, C2, C3, cb2, tau + 3);
                TILECOMP(bh0, bh1, bl0, bl1, c2v, (tau + 1) * 16 + m)
            }
        }

        // ---- reduce across the 16 col-lanes (k-tie: lowest k) ----
#pragma unroll
        for (int off = 1; off < 16; off <<= 1) {
#pragma unroll
            for (int j = 0; j < 4; ++j) {
                float o1 = __shfl_xor(b1a[j], off); int ok = __shfl_xor(k1a[j], off);
                float o2 = __shfl_xor(b2a[j], off);
                float n2 = fminf(fminf(b2a[j], o2), fmaxf(b1a[j], o1));
                bool tk = (o1 < b1a[j]) || (o1 == b1a[j] && ok < k1a[j]);
                k1a[j] = tk ? ok : k1a[j]; b1a[j] = fminf(b1a[j], o1); b2a[j] = n2;
                o1 = __shfl_xor(b1b[j], off); ok = __shfl_xor(k1b[j], off);
                o2 = __shfl_xor(b2b[j], off);
                n2 = fminf(fminf(b2b[j], o2), fmaxf(b1b[j], o1));
                tk = (o1 < b1b[j]) || (o1 == b1b[j] && ok < k1b[j]);
                k1b[j] = tk ? ok : k1b[j]; b1b[j] = fminf(b1b[j], o1); b2b[j] = n2;
            }
        }

        // ---- δ-rescue: exact fp32 rescan of ambiguous rows (rare) ----
        const float* cr0 = cbf + (size_t)s * 65536;
#define RESCUE(b1X, b2X, k1X, R0, R1)                                         \
        for (int j = 0; j < 4; ++j) {                                         \
            unsigned long long mask = __ballot(b2X[j] - b1X[j] < DELTA);      \
            while (mask) {                                                    \
                int lq = (int)(__builtin_ctzll(mask)) >> 4;                   \
                mask &= ~(0xFFFFULL << (lq * 16));                            \
                int mrow = lq * 4 + j;                                        \
                float bd = 3.4e38f; int bk = 0;                               \
                for (int cc = 0; cc < 16; ++cc) {                             \
                    int n = cc * 64 + lane;                                   \
                    const float* crow = cr0 + (size_t)n * 64;                 \
                    float dot = 0.f;                                          \
                    for (int p = 0; p < 4; ++p) {                             \
                        for (int i = 0; i < 8; ++i)                           \
                            dot = fmaf(__shfl(R0[i], mrow + 16*p), crow[p*8+i], dot); \
                        for (int i = 0; i < 8; ++i)                           \
                            dot = fmaf(__shfl(R1[i], mrow + 16*p), crow[32+p*8+i], dot); \
                    }                                                         \
                    float sc = c2s[n] - 2.f * dot;                            \
                    if (sc < bd) { bd = sc; bk = n; }                         \
                }                                                             \
                for (int off = 1; off < 64; off <<= 1) {                      \
                    float ob = __shfl_xor(bd, off); int ok = __shfl_xor(bk, off); \
                    bool tk = (ob < bd) || (ob == bd && ok < bk);             \
                    bk = tk ? ok : bk; bd = fminf(bd, ob);                    \
                }                                                             \
                if (q == lq) k1X[j] = bk;                                     \
            }                                                                 \
        }
        RESCUE(b1a, b2a, k1a, ra0, ra1)
        RESCUE(b1b, b2b, k1b, rb0, rb1)
#undef RESCUE

        // ---- transpose winners to per-lane rows (row = m), convergent ----
        int mm = m & 3, src = (m >> 2) * 16;
        int wa0 = __shfl(k1a[0], src), wa1 = __shfl(k1a[1], src);
        int wa2 = __shfl(k1a[2], src), wa3 = __shfl(k1a[3], src);
        int bka = (mm == 0) ? wa0 : (mm == 1) ? wa1 : (mm == 2) ? wa2 : wa3;
        int wb0 = __shfl(k1b[0], src), wb1 = __shfl(k1b[1], src);
        int wb2 = __shfl(k1b[2], src), wb3 = __shfl(k1b[3], src);
        int bkb = (mm == 0) ? wb0 : (mm == 1) ? wb1 : (mm == 2) ? wb2 : wb3;

        // ---- fp32 residual update ----
        const float* qa = cbf + (size_t)s * 65536 + (size_t)bka * 64;
        const float* qb = cbf + (size_t)s * 65536 + (size_t)bkb * 64;
#pragma unroll
        for (int i = 0; i < 8; ++i) {
            ra0[i] -= qa[q*8+i];  ra1[i] -= qa[32+q*8+i];
            rb0[i] -= qb[q*8+i];  rb1[i] -= qb[32+q*8+i];
        }

        // ---- loss: plain per-wave store (summed in finalize) ----
        float ls = 0.f;
#pragma unroll
        for (int i = 0; i < 8; ++i) {
            ls = fmaf(ra0[i], ra0[i], ls); ls = fmaf(ra1[i], ra1[i], ls);
            ls = fmaf(rb0[i], rb0[i], ls); ls = fmaf(rb1[i], rb1[i], ls);
        }
#pragma unroll
        for (int off = 1; off < 64; off <<= 1) ls += __shfl_xor(ls, off);
        if (lane == 0) lossp[s * NW + wid] = ls;

        // ---- histogram: bka/bkb are per-vector winners (dup across q) ----
        if (q == 0) {
            atomicAdd(&cnt[s * K + bka], 1u);   // vector vbase+m
            atomicAdd(&cnt[s * K + bkb], 1u);   // vector vbase+16+m
        }
    }
#undef TILECOMP
#undef LOADTILE

    // ---- epilogue: zq = z - r_final ----
#pragma unroll
    for (int i = 0; i < 8; ++i) {
        size_t a0 = zrow + ((size_t)(q*8+i)    << 12) + ta;
        size_t a1 = zrow + ((size_t)(32+q*8+i) << 12) + ta;
        zq[a0] = z[a0] - ra0[i];
        zq[a1] = z[a1] - ra1[i];
        size_t a2 = zrow + ((size_t)(q*8+i)    << 12) + tb;
        size_t a3 = zrow + ((size_t)(32+q*8+i) << 12) + tb;
        zq[a2] = z[a2] - rb0[i];
        zq[a3] = z[a3] - rb1[i];
    }
}

// ---------------------------------------------------------------------------
// Finalize: losses (mean of summed wave partials) + perplexities
// ---------------------------------------------------------------------------
__global__ void rvq_finalize(const float* __restrict__ lossp,
                             const unsigned* __restrict__ cnt,
                             float* __restrict__ out_loss,
                             float* __restrict__ out_perp) {
    const int s   = blockIdx.x;
    const int tid = threadIdx.x;
    float ent = 0.f, lsum = 0.f;
    for (int i = tid; i < K; i += 256) {
        float p = (float)cnt[s * K + i] * (1.0f / 65536.0f);
        ent += p * logf(p + EPSQ);
    }
    for (int i = tid; i < NW; i += 256) lsum += lossp[s * NW + i];
    __shared__ float redE[4], redL[4];
#pragma unroll
    for (int off = 32; off > 0; off >>= 1) {
        ent  += __shfl_down(ent, off);
        lsum += __shfl_down(lsum, off);
    }
    if ((tid & 63) == 0) { redE[tid >> 6] = ent; redL[tid >> 6] = lsum; }
    __syncthreads();
    if (tid == 0) {
        float te = redE[0] + redE[1] + redE[2] + redE[3];
        float tl = redL[0] + redL[1] + redL[2] + redL[3];
        out_perp[s] = expf(-te);
        out_loss[s] = tl * (1.0f / NELEM);
    }
}

// ---------------------------------------------------------------------------
extern "C" void kernel_launch(void* const* d_in, const int* in_sizes, int n_in,
                              void* d_out, int out_size, void* d_ws, size_t ws_size,
                              hipStream_t stream) {
    const float* z  = (const float*)d_in[0];
    const float* cb = (const float*)d_in[1];

    float* zq       = (float*)d_out;
    float* out_loss = zq + 4194304;
    float* out_perp = out_loss + 8;

    // ws: cbi 2 MB | c2 32 KB | cnt 32 KB | lossp 64 KB
    char* ws = (char*)d_ws;
    unsigned short* cbi = (unsigned short*)(ws);
    float*    c2    = (float*)(ws + 2097152);
    unsigned* cnt   = (unsigned*)(ws + 2129920);
    float*    lossp = (float*)(ws + 2162688);

    hipLaunchKernelGGL(rvq_prep,     dim3(128),  dim3(256), 0, stream, cb, cbi, c2, cnt);
    hipLaunchKernelGGL(rvq_main,     dim3(NW),   dim3(64),  0, stream, z, cb, cbi, c2, zq, lossp, cnt);
    hipLaunchKernelGGL(rvq_finalize, dim3(S),    dim3(256), 0, stream, lossp, cnt, out_loss, out_perp);
}